// Round 1
// baseline (142.992 us; speedup 1.0000x reference)
//
#include <hip/hip_runtime.h>

// SpiralConv: out[b,t,d] = Re( phazor_init[d] * sum_{s<=t} phazor[d]^(t-s) x[b,s,d]
//                              + last_conv[b,d] * phazor[d]^(t+1) )
// == first-order complex linear recurrence g[t] = a*g[t-1] + init*x[t], g[-1]=last_conv.
// Implemented as a 3-pass chunked scan (chunk=64, K=64 chunks), memory-bound.

#define BB 4
#define LL 4096
#define DD 1024
#define CHUNK 64
#define KK (LL / CHUNK)   // 64

__device__ __forceinline__ void phazor_of(float pr, float pi, float& ar, float& ai) {
    float mag = sqrtf(pr * pr + pi * pi);
    float s = expf(-mag) / mag;   // phazor = p/|p| * exp(-|p|)
    ar = pr * s;
    ai = pi * s;
}

// Pass 1: per (b, chunk, d): local scan with zero init -> S[b,k,d] (complex)
__global__ __launch_bounds__(256) void spiral_pass1(
    const float* __restrict__ x,
    const float* __restrict__ p_re, const float* __restrict__ p_im,
    const float* __restrict__ in_re, const float* __restrict__ in_im,
    float2* __restrict__ S)
{
    int tid = blockIdx.x * 256 + threadIdx.x;
    int dq = tid & (DD / 4 - 1);          // 0..255  (d quad)
    int k  = (tid >> 8) & (KK - 1);       // 0..63
    int b  = tid >> 14;                   // 0..3
    int d0 = dq * 4;

    float4 prv = *(const float4*)(p_re + d0);
    float4 piv = *(const float4*)(p_im + d0);
    float4 brv = *(const float4*)(in_re + d0);
    float4 biv = *(const float4*)(in_im + d0);
    float ar[4], ai[4];
    float br[4] = {brv.x, brv.y, brv.z, brv.w};
    float bi[4] = {biv.x, biv.y, biv.z, biv.w};
    {
        float prs[4] = {prv.x, prv.y, prv.z, prv.w};
        float pis[4] = {piv.x, piv.y, piv.z, piv.w};
#pragma unroll
        for (int q = 0; q < 4; ++q) phazor_of(prs[q], pis[q], ar[q], ai[q]);
    }

    float sr[4] = {0.f, 0.f, 0.f, 0.f};
    float si[4] = {0.f, 0.f, 0.f, 0.f};
    const float* xp = x + ((size_t)(b * LL + k * CHUNK) * DD + d0);

    for (int t0 = 0; t0 < CHUNK; t0 += 8) {
        float4 xv[8];
#pragma unroll
        for (int j = 0; j < 8; ++j)
            xv[j] = *(const float4*)(xp + (size_t)(t0 + j) * DD);
#pragma unroll
        for (int j = 0; j < 8; ++j) {
            float xs[4] = {xv[j].x, xv[j].y, xv[j].z, xv[j].w};
#pragma unroll
            for (int q = 0; q < 4; ++q) {
                float nr = fmaf(ar[q], sr[q], fmaf(-ai[q], si[q], br[q] * xs[q]));
                float ni = fmaf(ar[q], si[q], fmaf( ai[q], sr[q], bi[q] * xs[q]));
                sr[q] = nr; si[q] = ni;
            }
        }
    }

    float2* Sp = S + ((size_t)(b * KK + k) * DD + d0);
#pragma unroll
    for (int q = 0; q < 4; ++q) Sp[q] = make_float2(sr[q], si[q]);
}

// Pass 2: per (b, d): scan over chunks -> chunk initial states C0[b,k,d]
__global__ __launch_bounds__(256) void spiral_pass2(
    const float* __restrict__ p_re, const float* __restrict__ p_im,
    const float* __restrict__ lc_re, const float* __restrict__ lc_im,
    const float2* __restrict__ S,
    float2* __restrict__ C0)
{
    int tid = blockIdx.x * 256 + threadIdx.x;
    int d = tid & (DD - 1);
    int b = tid >> 10;

    float ar, ai;
    phazor_of(p_re[d], p_im[d], ar, ai);
    // aC = a^CHUNK (CHUNK = 64 = 2^6) via repeated squaring
    float qr = ar, qi = ai;
#pragma unroll
    for (int i = 0; i < 6; ++i) {
        float nr = qr * qr - qi * qi;
        float ni = 2.f * qr * qi;
        qr = nr; qi = ni;
    }

    float cr = lc_re[b * DD + d];
    float ci = lc_im[b * DD + d];
#pragma unroll
    for (int k = 0; k < KK; ++k) {
        size_t idx = (size_t)(b * KK + k) * DD + d;
        C0[idx] = make_float2(cr, ci);
        float2 s = S[idx];
        float nr = fmaf(qr, cr, fmaf(-qi, ci, s.x));
        float ni = fmaf(qr, ci, fmaf( qi, cr, s.y));
        cr = nr; ci = ni;
    }
}

// Pass 3: per (b, chunk, d): replay recurrence from true init, write Re(g)
__global__ __launch_bounds__(256) void spiral_pass3(
    const float* __restrict__ x,
    const float* __restrict__ p_re, const float* __restrict__ p_im,
    const float* __restrict__ in_re, const float* __restrict__ in_im,
    const float2* __restrict__ C0,
    float* __restrict__ out)
{
    int tid = blockIdx.x * 256 + threadIdx.x;
    int dq = tid & (DD / 4 - 1);
    int k  = (tid >> 8) & (KK - 1);
    int b  = tid >> 14;
    int d0 = dq * 4;

    float4 prv = *(const float4*)(p_re + d0);
    float4 piv = *(const float4*)(p_im + d0);
    float4 brv = *(const float4*)(in_re + d0);
    float4 biv = *(const float4*)(in_im + d0);
    float ar[4], ai[4];
    float br[4] = {brv.x, brv.y, brv.z, brv.w};
    float bi[4] = {biv.x, biv.y, biv.z, biv.w};
    {
        float prs[4] = {prv.x, prv.y, prv.z, prv.w};
        float pis[4] = {piv.x, piv.y, piv.z, piv.w};
#pragma unroll
        for (int q = 0; q < 4; ++q) phazor_of(prs[q], pis[q], ar[q], ai[q]);
    }

    float cr[4], ci[4];
    const float2* Cp = C0 + ((size_t)(b * KK + k) * DD + d0);
#pragma unroll
    for (int q = 0; q < 4; ++q) { float2 c = Cp[q]; cr[q] = c.x; ci[q] = c.y; }

    const size_t base = (size_t)(b * LL + k * CHUNK) * DD + d0;
    const float* xp = x + base;
    float* op = out + base;

    for (int t0 = 0; t0 < CHUNK; t0 += 8) {
        float4 xv[8];
#pragma unroll
        for (int j = 0; j < 8; ++j)
            xv[j] = *(const float4*)(xp + (size_t)(t0 + j) * DD);
#pragma unroll
        for (int j = 0; j < 8; ++j) {
            float xs[4] = {xv[j].x, xv[j].y, xv[j].z, xv[j].w};
            float os[4];
#pragma unroll
            for (int q = 0; q < 4; ++q) {
                float nr = fmaf(ar[q], cr[q], fmaf(-ai[q], ci[q], br[q] * xs[q]));
                float ni = fmaf(ar[q], ci[q], fmaf( ai[q], cr[q], bi[q] * xs[q]));
                cr[q] = nr; ci[q] = ni;
                os[q] = nr;
            }
            *(float4*)(op + (size_t)(t0 + j) * DD) = make_float4(os[0], os[1], os[2], os[3]);
        }
    }
}

extern "C" void kernel_launch(void* const* d_in, const int* in_sizes, int n_in,
                              void* d_out, int out_size, void* d_ws, size_t ws_size,
                              hipStream_t stream) {
    const float* x      = (const float*)d_in[0];
    const float* p_re   = (const float*)d_in[1];
    const float* p_im   = (const float*)d_in[2];
    const float* pin_re = (const float*)d_in[3];
    const float* pin_im = (const float*)d_in[4];
    const float* lc_re  = (const float*)d_in[5];
    const float* lc_im  = (const float*)d_in[6];
    float* out = (float*)d_out;

    float2* S  = (float2*)d_ws;                      // B*K*D complex = 2 MiB
    float2* C0 = S + (size_t)BB * KK * DD;           // B*K*D complex = 2 MiB

    const int threads13 = BB * KK * (DD / 4);        // 65536
    dim3 blk(256);
    dim3 grid13(threads13 / 256);                    // 256 blocks
    dim3 grid2((BB * DD) / 256);                     // 16 blocks

    spiral_pass1<<<grid13, blk, 0, stream>>>(x, p_re, p_im, pin_re, pin_im, S);
    spiral_pass2<<<grid2,  blk, 0, stream>>>(p_re, p_im, lc_re, lc_im, S, C0);
    spiral_pass3<<<grid13, blk, 0, stream>>>(x, p_re, p_im, pin_re, pin_im, C0, out);
}